// Round 1
// baseline (421.400 us; speedup 1.0000x reference)
//
#include <hip/hip_runtime.h>

// Problem: x[16384, 4096] fp32, diag[4096] fp32.
// out0[b,d] = x[b,d] * exp(diag[d])   (16384*4096 floats)
// out1[d]   = diag[d]                 (4096 floats, concatenated after out0)

constexpr int D    = 4096;
constexpr int B    = 16384;
constexpr int RPT  = 8;            // rows per thread (amortizes exp + addr calc)
constexpr int COL4 = D / 4;        // 1024 float4 columns per row
constexpr int ROWG = B / RPT;      // 2048 row-groups
constexpr int BLK  = 256;
constexpr int GRID = COL4 * ROWG / BLK;  // 8192 blocks

__global__ __launch_bounds__(BLK) void ScaleLayer_54906861912422_kernel(
    const float4* __restrict__ x4,
    const float4* __restrict__ diag4,
    float4* __restrict__ out4,
    float4* __restrict__ tail4) {
  int t  = blockIdx.x * BLK + threadIdx.x;
  int c  = t & (COL4 - 1);   // float4-column index
  int rg = t >> 10;          // row-group index (t / COL4)

  // Per-thread scale for its 4 columns, computed once, reused across RPT rows.
  float4 dv = diag4[c];
  float4 s;
  s.x = expf(dv.x);
  s.y = expf(dv.y);
  s.z = expf(dv.z);
  s.w = expf(dv.w);

  size_t base = (size_t)rg * RPT * COL4 + (size_t)c;
#pragma unroll
  for (int r = 0; r < RPT; ++r) {
    size_t idx = base + (size_t)r * COL4;
    float4 v = x4[idx];
    v.x *= s.x;
    v.y *= s.y;
    v.z *= s.z;
    v.w *= s.w;
    out4[idx] = v;
  }

  // Second tuple output: raw diag passthrough. rg==0 threads have c==t,
  // so dv already holds diag4[t].
  if (t < COL4) tail4[t] = dv;
}

extern "C" void kernel_launch(void* const* d_in, const int* in_sizes, int n_in,
                              void* d_out, int out_size, void* d_ws, size_t ws_size,
                              hipStream_t stream) {
  const float* x    = (const float*)d_in[0];
  const float* diag = (const float*)d_in[1];
  float* out  = (float*)d_out;
  float* tail = out + (size_t)B * D;  // 256 MiB offset -> still 16B aligned

  ScaleLayer_54906861912422_kernel<<<GRID, BLK, 0, stream>>>(
      (const float4*)x, (const float4*)diag, (float4*)out, (float4*)tail);
}